// Round 6
// baseline (231.472 us; speedup 1.0000x reference)
//
#include <hip/hip_runtime.h>
#include <hip/hip_bf16.h>
#include <stdint.h>

// Round 6: conv spill fix. Phase-split (Q then KV) keeps live VGPRs < 128;
// transposed conv weights give coalesced weight loads. z-chunk x2.
// R5 post-mortem: VGPR=80 vs >=135 live floats => spills => latency-bound.
// Rest identical to round 5.

typedef _Float16 f16;
typedef _Float16 f16x8 __attribute__((ext_vector_type(8)));
typedef float f32x4 __attribute__((ext_vector_type(4)));
typedef uint32_t u32;

#define NC 384
#define MFMA16(A_,B_,C_) __builtin_amdgcn_mfma_f32_16x16x32_f16((A_),(B_),(C_),0,0,0)

// ---------------- weight fp32 -> f16 convert ----------------
__global__ __launch_bounds__(256) void cvt_w(
    const float* __restrict__ s0, const float* __restrict__ s1,
    const float* __restrict__ s2, const float* __restrict__ s3,
    f16* __restrict__ d0, f16* __restrict__ d1,
    f16* __restrict__ d2, f16* __restrict__ d3, int n)
{
  int i = blockIdx.x * 256 + threadIdx.x;
  if (i < n) { d0[i] = (f16)s0[i]; d1[i] = (f16)s1[i]; d2[i] = (f16)s2[i]; d3[i] = (f16)s3[i]; }
}

// ---------------- conv-weight transpose [384][27] -> [27][384] ----------------
__global__ __launch_bounds__(384) void cvt_wt(
    const float* __restrict__ wq, const float* __restrict__ wk, const float* __restrict__ wv,
    float* __restrict__ qT, float* __restrict__ kT, float* __restrict__ vT)
{
  const int c = threadIdx.x;
  const int t = blockIdx.x;   // 0..26
  qT[t * 384 + c] = wq[c * 27 + t];
  kT[t * 384 + c] = wk[c * 27 + t];
  vT[t * 384 + c] = wv[c * 27 + t];
}

// ---------------- fused depthwise conv3d + BN, phase-split ----------------
// 384 thr = channel; grid (64 hw-tiles, 8 b, 2 z-chunks of 8).
// Phase Q: 2x2 (h,w) tile, 4x4x3 ring window, 27 weight regs.
// Phase KV: single even point (h0,w0), 3x3x3 ring window, 54 weight regs.
__global__ __launch_bounds__(384) void conv_fused(
    const float* __restrict__ x,
    const float* __restrict__ wqT, const float* __restrict__ wkT, const float* __restrict__ wvT,
    const float* __restrict__ bqg, const float* __restrict__ bqb,
    const float* __restrict__ bqm, const float* __restrict__ bqv,
    const float* __restrict__ bkg, const float* __restrict__ bkb,
    const float* __restrict__ bkm, const float* __restrict__ bkv,
    const float* __restrict__ bvg, const float* __restrict__ bvb,
    const float* __restrict__ bvm, const float* __restrict__ bvv,
    f16* __restrict__ qout, f16* __restrict__ kout, f16* __restrict__ vout)
{
  const int c = threadIdx.x;
  const int th = blockIdx.x >> 3, tw = blockIdx.x & 7;
  const int b = blockIdx.y;
  const int z0 = blockIdx.z * 8;
  const int h0 = th * 2, w0 = tw * 2;

  bool hok[4], wok[4];
#pragma unroll
  for (int a = 0; a < 4; ++a) {
    hok[a] = (unsigned)(h0 - 1 + a) < 16u;   // block-uniform
    wok[a] = (unsigned)(w0 - 1 + a) < 16u;
  }
  const float* xb = x + (size_t)b * 4096 * NC + c;
  const size_t qb = (size_t)b * 4096;

  // ================= Phase Q =================
  {
    float wqr[27];
#pragma unroll
    for (int t = 0; t < 27; ++t) wqr[t] = wqT[t * 384 + c];   // coalesced
    const float invq = bqg[c] * rsqrtf(bqv[c] + 1e-5f);
    const float betq = bqb[c] - bqm[c] * invq;

    float win[3][4][4];
    auto ldplane4 = [&](int s, int iz) {   // s literal after unroll
      const bool zok = (unsigned)iz < 16u;
#pragma unroll
      for (int a = 0; a < 4; ++a)
#pragma unroll
        for (int e = 0; e < 4; ++e) {
          float v = 0.f;
          if (zok && hok[a] && wok[e])
            v = xb[(size_t)((h0 - 1 + a) * 256 + (w0 - 1 + e) * 16 + iz) * NC];
          win[s][a][e] = v;
        }
    };
    ldplane4(0, z0 - 1);
    ldplane4(1, z0);
#pragma unroll
    for (int zr = 0; zr < 8; ++zr) {
      const int z = z0 + zr;
      ldplane4((zr + 2) % 3, z + 1);
      float aq00 = 0.f, aq01 = 0.f, aq10 = 0.f, aq11 = 0.f;
#pragma unroll
      for (int p = 0; p < 3; ++p) {
        const int s = (zr + p) % 3;   // compile-time
#pragma unroll
        for (int a = 0; a < 3; ++a)
#pragma unroll
          for (int e = 0; e < 3; ++e) {
            const float cq = wqr[a * 9 + e * 3 + p];
            aq00 += win[s][a][e]         * cq;
            aq01 += win[s][a][e + 1]     * cq;
            aq10 += win[s][a + 1][e]     * cq;
            aq11 += win[s][a + 1][e + 1] * cq;
          }
      }
      qout[(qb + (h0 + 0) * 256 + (w0 + 0) * 16 + z) * NC + c] = (f16)(aq00 * invq + betq);
      qout[(qb + (h0 + 0) * 256 + (w0 + 1) * 16 + z) * NC + c] = (f16)(aq01 * invq + betq);
      qout[(qb + (h0 + 1) * 256 + (w0 + 0) * 16 + z) * NC + c] = (f16)(aq10 * invq + betq);
      qout[(qb + (h0 + 1) * 256 + (w0 + 1) * 16 + z) * NC + c] = (f16)(aq11 * invq + betq);
    }
  }

  // fence: keep KV weight loads from hoisting into phase Q (register pressure)
  asm volatile("" ::: "memory");
  __builtin_amdgcn_sched_barrier(0);

  // ================= Phase KV =================
  {
    float wkr[27], wvr[27];
#pragma unroll
    for (int t = 0; t < 27; ++t) { wkr[t] = wkT[t * 384 + c]; wvr[t] = wvT[t * 384 + c]; }
    const float invk = bkg[c] * rsqrtf(bkv[c] + 1e-5f), betk = bkb[c] - bkm[c] * invk;
    const float invv = bvg[c] * rsqrtf(bvv[c] + 1e-5f), betv = bvb[c] - bvm[c] * invv;

    float wn[3][3][3];
    auto ldplane3 = [&](int s, int iz) {
      const bool zok = (unsigned)iz < 16u;
#pragma unroll
      for (int a = 0; a < 3; ++a)
#pragma unroll
        for (int e = 0; e < 3; ++e) {
          float v = 0.f;
          if (zok && hok[a] && wok[e])
            v = xb[(size_t)((h0 - 1 + a) * 256 + (w0 - 1 + e) * 16 + iz) * NC];
          wn[s][a][e] = v;
        }
    };
    // planes j=0..8 <-> iz = z0-1+j, slot j%3
    ldplane3(0, z0 - 1);
    ldplane3(1, z0);
    ldplane3(2, z0 + 1);
#pragma unroll
    for (int i = 0; i < 4; ++i) {
      float ak = 0.f, av = 0.f;
#pragma unroll
      for (int p = 0; p < 3; ++p) {
        const int s = (2 * i + p) % 3;   // compile-time
#pragma unroll
        for (int a = 0; a < 3; ++a)
#pragma unroll
          for (int e = 0; e < 3; ++e) {
            const float wv_ = wn[s][a][e];
            ak += wv_ * wkr[a * 9 + e * 3 + p];
            av += wv_ * wvr[a * 9 + e * 3 + p];
          }
      }
      const int z = z0 + 2 * i;
      const size_t t = (size_t)b * 512 + (th * 8 + tw) * 8 + (z >> 1);
      kout[t * NC + c] = (f16)(ak * invk + betk);
      vout[t * NC + c] = (f16)(av * invv + betv);
      if (i < 3) {
        ldplane3((2 * i + 3) % 3, z0 + 2 * i + 2);
        ldplane3((2 * i + 4) % 3, z0 + 2 * i + 3);
      }
    }
  }
}

// ---------------- GEMM: C[M,384] = A[M,384] * W[384,384]^T ----------------
template<int MODE>
__global__ __launch_bounds__(256) void gemm_bt(
    const f16* __restrict__ A, const f16* __restrict__ Bw,
    void* __restrict__ Cout, const float* __restrict__ bias)
{
  const int LDT = 72;
  __shared__ f16 As[128 * 72];
  __shared__ f16 Bs[128 * 72];
  const int tid = threadIdx.x;
  const int w = tid >> 6, lane = tid & 63;
  const int g = lane >> 4, q = lane & 15;
  const int wr = w >> 1, wc = w & 1;
  const size_t brow = (size_t)blockIdx.y * 128;
  const int bcol = blockIdx.x * 128;
  f32x4 acc[4][4] = {};
  for (int kt = 0; kt < 6; ++kt) {
    const int k0 = kt * 64;
    __syncthreads();
#pragma unroll
    for (int i = tid; i < 1024; i += 256) {
      const int row = i >> 3, blk = i & 7;
      *(f16x8*)&As[row * LDT + blk * 8] = *(const f16x8*)&A[(brow + row) * NC + k0 + blk * 8];
      *(f16x8*)&Bs[row * LDT + blk * 8] = *(const f16x8*)&Bw[((size_t)bcol + row) * NC + k0 + blk * 8];
    }
    __syncthreads();
#pragma unroll
    for (int ks = 0; ks < 2; ++ks) {
      f16x8 af[4], bfr[4];
#pragma unroll
      for (int m = 0; m < 4; ++m) {
        af[m]  = *(const f16x8*)&As[(wr * 64 + m * 16 + q) * LDT + (4 * ks + g) * 8];
        bfr[m] = *(const f16x8*)&Bs[(wc * 64 + m * 16 + q) * LDT + (4 * ks + g) * 8];
      }
#pragma unroll
      for (int m = 0; m < 4; ++m)
#pragma unroll
        for (int n = 0; n < 4; ++n)
          acc[m][n] = MFMA16(af[m], bfr[n], acc[m][n]);
    }
  }
  float bvals[4];
  if (MODE == 2) {
#pragma unroll
    for (int n = 0; n < 4; ++n) bvals[n] = bias[bcol + wc * 64 + n * 16 + q];
  }
#pragma unroll
  for (int m = 0; m < 4; ++m) {
#pragma unroll
    for (int n = 0; n < 4; ++n) {
#pragma unroll
      for (int r = 0; r < 4; ++r) {
        const size_t row = brow + wr * 64 + m * 16 + 4 * g + r;
        const int col = bcol + wc * 64 + n * 16 + q;
        const float v = acc[m][n][r];
        if (MODE == 0) {
          ((f16*)Cout)[row * NC + col] = (f16)v;
        } else if (MODE == 1) {
          const size_t bi = row >> 9, t = row & 511;
          ((f16*)Cout)[(bi * NC + col) * 512 + t] = (f16)v;
        } else {
          ((float*)Cout)[row * NC + col] = v + bvals[n];
        }
      }
    }
  }
}

// ---------------- flash attention (LDS P round-trip) ----------------
__global__ __launch_bounds__(512) void attn(
    const f16* __restrict__ Qp, const f16* __restrict__ Kp,
    const f16* __restrict__ Vt, f16* __restrict__ O)
{
  const int LK = 72;
  const int LV = 136;
  const int LP = 136;
  __shared__ f16 Ks[128 * 72];
  __shared__ f16 Vs[64 * 136];
  __shared__ f16 Ps[8 * 16 * 136];
  const int tid = threadIdx.x;
  const int w = tid >> 6, lane = tid & 63;
  const int g = lane >> 4, q = lane & 15;
  const int qt = blockIdx.x, h = blockIdx.y, b = blockIdx.z;
  const float sc = 0.051031036307982884f * 1.4426950408889634f;
  const size_t qrow0 = (size_t)b * 4096 + qt * 128 + w * 16;
  f16x8 qf[2];
#pragma unroll
  for (int ks = 0; ks < 2; ++ks)
    qf[ks] = *(const f16x8*)(Qp + (qrow0 + q) * NC + h * 64 + ks * 32 + g * 8);
  f32x4 oa[4] = {};
  float m_run = -INFINITY, l_run = 0.f;
  for (int ch = 0; ch < 4; ++ch) {
    const size_t kb = (size_t)b * 512 + ch * 128;
    __syncthreads();
#pragma unroll
    for (int i = tid; i < 1024; i += 512) {
      const int j = i >> 3, blk = i & 7;
      *(f16x8*)&Ks[j * LK + blk * 8] = *(const f16x8*)&Kp[(kb + j) * NC + h * 64 + blk * 8];
    }
#pragma unroll
    for (int i = tid; i < 1024; i += 512) {
      const int dh = i >> 4, blk = i & 15;
      *(f16x8*)&Vs[dh * LV + blk * 8] =
          *(const f16x8*)&Vt[((size_t)b * NC + h * 64 + dh) * 512 + ch * 128 + blk * 8];
    }
    __syncthreads();
    f32x4 st[8] = {};
#pragma unroll
    for (int ks = 0; ks < 2; ++ks) {
#pragma unroll
      for (int m = 0; m < 8; ++m) {
        const f16x8 kf = *(const f16x8*)&Ks[(m * 16 + q) * LK + (4 * ks + g) * 8];
        st[m] = MFMA16(kf, qf[ks], st[m]);
      }
    }
    float tv[8][4];
    float cmax = -INFINITY;
#pragma unroll
    for (int m = 0; m < 8; ++m)
#pragma unroll
      for (int r = 0; r < 4; ++r) { tv[m][r] = st[m][r] * sc; cmax = fmaxf(cmax, tv[m][r]); }
    cmax = fmaxf(cmax, __shfl_xor(cmax, 16));
    cmax = fmaxf(cmax, __shfl_xor(cmax, 32));
    const float mnew = fmaxf(m_run, cmax);
    const float fac = exp2f(m_run - mnew);
    float psum = 0.f;
#pragma unroll
    for (int m = 0; m < 8; ++m) {
      const float p0 = exp2f(tv[m][0] - mnew), p1 = exp2f(tv[m][1] - mnew);
      const float p2 = exp2f(tv[m][2] - mnew), p3 = exp2f(tv[m][3] - mnew);
      psum += (p0 + p1) + (p2 + p3);
      f16* pr = &Ps[(w * 16 + q) * LP + m * 16 + 4 * g];
      pr[0] = (f16)p0; pr[1] = (f16)p1; pr[2] = (f16)p2; pr[3] = (f16)p3;
    }
    psum += __shfl_xor(psum, 16);
    psum += __shfl_xor(psum, 32);
    l_run = l_run * fac + psum;
    m_run = mnew;
#pragma unroll
    for (int r = 0; r < 4; ++r) {
      const float fr = __shfl(fac, g * 4 + r);
#pragma unroll
      for (int n = 0; n < 4; ++n) oa[n][r] *= fr;
    }
    __syncthreads();
#pragma unroll
    for (int ks = 0; ks < 4; ++ks) {
      const f16x8 pa = *(const f16x8*)&Ps[(w * 16 + q) * LP + ks * 32 + g * 8];
#pragma unroll
      for (int n = 0; n < 4; ++n) {
        const f16x8 vf = *(const f16x8*)&Vs[(n * 16 + q) * LV + ks * 32 + g * 8];
        oa[n] = MFMA16(pa, vf, oa[n]);
      }
    }
  }
  const float linv = 1.0f / l_run;
#pragma unroll
  for (int r = 0; r < 4; ++r) {
    const float lr = __shfl(linv, g * 4 + r);
    const size_t row = qrow0 + 4 * g + r;
#pragma unroll
    for (int n = 0; n < 4; ++n)
      O[row * NC + h * 64 + n * 16 + q] = (f16)(oa[n][r] * lr);
  }
}

// ---------------- launch ----------------
extern "C" void kernel_launch(void* const* d_in, const int* in_sizes, int n_in,
                              void* d_out, int out_size, void* d_ws, size_t ws_size,
                              hipStream_t stream) {
  const float* x   = (const float*)d_in[0];
  const float* cqw = (const float*)d_in[1];
  const float* ckw = (const float*)d_in[2];
  const float* cvw = (const float*)d_in[3];
  const float* bqg = (const float*)d_in[4],  *bqb = (const float*)d_in[5];
  const float* bqm = (const float*)d_in[6],  *bqv = (const float*)d_in[7];
  const float* bkg = (const float*)d_in[8],  *bkb = (const float*)d_in[9];
  const float* bkm = (const float*)d_in[10], *bkv = (const float*)d_in[11];
  const float* bvg = (const float*)d_in[12], *bvb = (const float*)d_in[13];
  const float* bvm = (const float*)d_in[14], *bvv = (const float*)d_in[15];
  const float* wq = (const float*)d_in[16];
  const float* wk = (const float*)d_in[17];
  const float* wv = (const float*)d_in[18];
  const float* pw = (const float*)d_in[19];
  const float* pb = (const float*)d_in[20];

  f16* q_tok = (f16*)d_out;                              // lo half (25 MB)
  f16* Qp    = (f16*)((char*)d_out + 25165824);          // hi half (25 MB)

  char* ws = (char*)d_ws;
  f16* wq_h  = (f16*)(ws + 0);
  f16* wk_h  = (f16*)(ws + 294912);
  f16* wv_h  = (f16*)(ws + 589824);
  f16* pw_h  = (f16*)(ws + 884736);
  f16* k_tok = (f16*)(ws + 1179648);
  f16* v_tok = (f16*)(ws + 4325376);
  f16* Kp    = (f16*)(ws + 7471104);
  f16* Vt    = (f16*)(ws + 10616832);
  f16* Oi    = (f16*)(ws + 13762560);
  float* wqT = (float*)(ws + 38928384);   // 41472 B each
  float* wkT = (float*)(ws + 38969856);
  float* wvT = (float*)(ws + 39011328);   // ws total 39,052,800 B

  cvt_w<<<dim3(576), dim3(256), 0, stream>>>(wq, wk, wv, pw, wq_h, wk_h, wv_h, pw_h, 147456);
  cvt_wt<<<dim3(27), dim3(384), 0, stream>>>(cqw, ckw, cvw, wqT, wkT, wvT);
  conv_fused<<<dim3(64, 8, 2), dim3(384), 0, stream>>>(
      x, wqT, wkT, wvT,
      bqg, bqb, bqm, bqv, bkg, bkb, bkm, bkv, bvg, bvb, bvm, bvv,
      q_tok, k_tok, v_tok);
  gemm_bt<0><<<dim3(3, 256), dim3(256), 0, stream>>>(q_tok, wq_h, Qp, nullptr);
  gemm_bt<0><<<dim3(3, 32),  dim3(256), 0, stream>>>(k_tok, wk_h, Kp, nullptr);
  gemm_bt<1><<<dim3(3, 32),  dim3(256), 0, stream>>>(v_tok, wv_h, Vt, nullptr);
  attn<<<dim3(32, 6, 8), dim3(512), 0, stream>>>(Qp, Kp, Vt, Oi);
  gemm_bt<2><<<dim3(3, 256), dim3(256), 0, stream>>>(Oi, pw_h, d_out, pb);
}

// Round 7
// 200.725 us; speedup vs baseline: 1.1532x; 1.1532x over previous
//
#include <hip/hip_runtime.h>
#include <hip/hip_bf16.h>
#include <stdint.h>

// Round 7: conv register-budget fix. R6 post-mortem: compiler REMATERIALIZES
// weight loads in the z-loop to hit its default occupancy target (VGPR 52-80,
// LDS spill block). Fix = __launch_bounds__(384, 2) (VGPR cap 256) on the R5
// single-phase body + coalesced transposed weights. Rest identical.

typedef _Float16 f16;
typedef _Float16 f16x8 __attribute__((ext_vector_type(8)));
typedef float f32x4 __attribute__((ext_vector_type(4)));
typedef uint32_t u32;

#define NC 384
#define MFMA16(A_,B_,C_) __builtin_amdgcn_mfma_f32_16x16x32_f16((A_),(B_),(C_),0,0,0)

// ---------------- weight fp32 -> f16 convert ----------------
__global__ __launch_bounds__(256) void cvt_w(
    const float* __restrict__ s0, const float* __restrict__ s1,
    const float* __restrict__ s2, const float* __restrict__ s3,
    f16* __restrict__ d0, f16* __restrict__ d1,
    f16* __restrict__ d2, f16* __restrict__ d3, int n)
{
  int i = blockIdx.x * 256 + threadIdx.x;
  if (i < n) { d0[i] = (f16)s0[i]; d1[i] = (f16)s1[i]; d2[i] = (f16)s2[i]; d3[i] = (f16)s3[i]; }
}

// ---------------- conv-weight transpose [384][27] -> [27][384] ----------------
__global__ __launch_bounds__(384) void cvt_wt(
    const float* __restrict__ wq, const float* __restrict__ wk, const float* __restrict__ wv,
    float* __restrict__ qT, float* __restrict__ kT, float* __restrict__ vT)
{
  const int c = threadIdx.x;
  const int t = blockIdx.x;   // 0..26
  qT[t * 384 + c] = wq[c * 27 + t];
  kT[t * 384 + c] = wk[c * 27 + t];
  vT[t * 384 + c] = wv[c * 27 + t];
}

// ---------------- fused depthwise conv3d + BN, single-phase ----------------
// 384 thr = channel; grid (64 hw-tiles, 8 b, 2 z-chunks of 8). 2x2 (h,w) tile,
// 3-plane ring window (compile-time slots). launch_bounds(384,2): VGPR cap 256
// so the ~170-reg live set (81 wgt + 48 window + accs) stays in registers.
__global__ __launch_bounds__(384, 2) void conv_fused(
    const float* __restrict__ x,
    const float* __restrict__ wqT, const float* __restrict__ wkT, const float* __restrict__ wvT,
    const float* __restrict__ bqg, const float* __restrict__ bqb,
    const float* __restrict__ bqm, const float* __restrict__ bqv,
    const float* __restrict__ bkg, const float* __restrict__ bkb,
    const float* __restrict__ bkm, const float* __restrict__ bkv,
    const float* __restrict__ bvg, const float* __restrict__ bvb,
    const float* __restrict__ bvm, const float* __restrict__ bvv,
    f16* __restrict__ qout, f16* __restrict__ kout, f16* __restrict__ vout)
{
  const int c = threadIdx.x;
  const int th = blockIdx.x >> 3, tw = blockIdx.x & 7;
  const int b = blockIdx.y;
  const int z0 = blockIdx.z * 8;
  const int h0 = th * 2, w0 = tw * 2;

  float wqr[27], wkr[27], wvr[27];
#pragma unroll
  for (int t = 0; t < 27; ++t) {
    wqr[t] = wqT[t * 384 + c];   // coalesced
    wkr[t] = wkT[t * 384 + c];
    wvr[t] = wvT[t * 384 + c];
  }
  const float invq = bqg[c] * rsqrtf(bqv[c] + 1e-5f), betq = bqb[c] - bqm[c] * invq;
  const float invk = bkg[c] * rsqrtf(bkv[c] + 1e-5f), betk = bkb[c] - bkm[c] * invk;
  const float invv = bvg[c] * rsqrtf(bvv[c] + 1e-5f), betv = bvb[c] - bvm[c] * invv;

  bool hok[4], wok[4];
#pragma unroll
  for (int a = 0; a < 4; ++a) {
    hok[a] = (unsigned)(h0 - 1 + a) < 16u;   // block-uniform
    wok[a] = (unsigned)(w0 - 1 + a) < 16u;
  }
  const float* xb = x + (size_t)b * 4096 * NC + c;

  float win[3][4][4];
  auto ldplane = [&](int s, int iz) {   // s compile-time; iz runtime (address only)
    const bool zok = (unsigned)iz < 16u;  // block-uniform
#pragma unroll
    for (int a = 0; a < 4; ++a)
#pragma unroll
      for (int e = 0; e < 4; ++e) {
        float v = 0.f;
        if (zok && hok[a] && wok[e])
          v = xb[(size_t)((h0 - 1 + a) * 256 + (w0 - 1 + e) * 16 + iz) * NC];
        win[s][a][e] = v;
      }
  };
  ldplane(2, z0 - 1);
  ldplane(0, z0);

#pragma unroll
  for (int zr = 0; zr < 8; ++zr) {
    const int z = z0 + zr;             // absolute z (runtime, address-only)
    const int snew = (zr + 1) % 3;     // compile-time slot
    ldplane(snew, z + 1);
    float aq00 = 0.f, aq01 = 0.f, aq10 = 0.f, aq11 = 0.f;
    float ak = 0.f, av = 0.f;
#pragma unroll
    for (int p = 0; p < 3; ++p) {
      const int s = (zr - 1 + p + 3) % 3;   // compile-time slot
#pragma unroll
      for (int a = 0; a < 3; ++a)
#pragma unroll
        for (int e = 0; e < 3; ++e) {
          const float w00 = win[s][a][e],     w01 = win[s][a][e + 1];
          const float w10 = win[s][a + 1][e], w11 = win[s][a + 1][e + 1];
          const float cq = wqr[a * 9 + e * 3 + p];
          aq00 += w00 * cq; aq01 += w01 * cq;
          aq10 += w10 * cq; aq11 += w11 * cq;
          if ((zr & 1) == 0) {               // z0 even -> z parity = zr parity
            ak += w00 * wkr[a * 9 + e * 3 + p];
            av += w00 * wvr[a * 9 + e * 3 + p];
          }
        }
    }
    const size_t qb = (size_t)b * 4096;
    qout[(qb + (h0 + 0) * 256 + (w0 + 0) * 16 + z) * NC + c] = (f16)(aq00 * invq + betq);
    qout[(qb + (h0 + 0) * 256 + (w0 + 1) * 16 + z) * NC + c] = (f16)(aq01 * invq + betq);
    qout[(qb + (h0 + 1) * 256 + (w0 + 0) * 16 + z) * NC + c] = (f16)(aq10 * invq + betq);
    qout[(qb + (h0 + 1) * 256 + (w0 + 1) * 16 + z) * NC + c] = (f16)(aq11 * invq + betq);
    if ((zr & 1) == 0) {
      const size_t t = (size_t)b * 512 + (th * 8 + tw) * 8 + (z >> 1);
      kout[t * NC + c] = (f16)(ak * invk + betk);
      vout[t * NC + c] = (f16)(av * invv + betv);
    }
  }
}

// ---------------- GEMM: C[M,384] = A[M,384] * W[384,384]^T ----------------
template<int MODE>
__global__ __launch_bounds__(256) void gemm_bt(
    const f16* __restrict__ A, const f16* __restrict__ Bw,
    void* __restrict__ Cout, const float* __restrict__ bias)
{
  const int LDT = 72;
  __shared__ f16 As[128 * 72];
  __shared__ f16 Bs[128 * 72];
  const int tid = threadIdx.x;
  const int w = tid >> 6, lane = tid & 63;
  const int g = lane >> 4, q = lane & 15;
  const int wr = w >> 1, wc = w & 1;
  const size_t brow = (size_t)blockIdx.y * 128;
  const int bcol = blockIdx.x * 128;
  f32x4 acc[4][4] = {};
  for (int kt = 0; kt < 6; ++kt) {
    const int k0 = kt * 64;
    __syncthreads();
#pragma unroll
    for (int i = tid; i < 1024; i += 256) {
      const int row = i >> 3, blk = i & 7;
      *(f16x8*)&As[row * LDT + blk * 8] = *(const f16x8*)&A[(brow + row) * NC + k0 + blk * 8];
      *(f16x8*)&Bs[row * LDT + blk * 8] = *(const f16x8*)&Bw[((size_t)bcol + row) * NC + k0 + blk * 8];
    }
    __syncthreads();
#pragma unroll
    for (int ks = 0; ks < 2; ++ks) {
      f16x8 af[4], bfr[4];
#pragma unroll
      for (int m = 0; m < 4; ++m) {
        af[m]  = *(const f16x8*)&As[(wr * 64 + m * 16 + q) * LDT + (4 * ks + g) * 8];
        bfr[m] = *(const f16x8*)&Bs[(wc * 64 + m * 16 + q) * LDT + (4 * ks + g) * 8];
      }
#pragma unroll
      for (int m = 0; m < 4; ++m)
#pragma unroll
        for (int n = 0; n < 4; ++n)
          acc[m][n] = MFMA16(af[m], bfr[n], acc[m][n]);
    }
  }
  float bvals[4];
  if (MODE == 2) {
#pragma unroll
    for (int n = 0; n < 4; ++n) bvals[n] = bias[bcol + wc * 64 + n * 16 + q];
  }
#pragma unroll
  for (int m = 0; m < 4; ++m) {
#pragma unroll
    for (int n = 0; n < 4; ++n) {
#pragma unroll
      for (int r = 0; r < 4; ++r) {
        const size_t row = brow + wr * 64 + m * 16 + 4 * g + r;
        const int col = bcol + wc * 64 + n * 16 + q;
        const float v = acc[m][n][r];
        if (MODE == 0) {
          ((f16*)Cout)[row * NC + col] = (f16)v;
        } else if (MODE == 1) {
          const size_t bi = row >> 9, t = row & 511;
          ((f16*)Cout)[(bi * NC + col) * 512 + t] = (f16)v;
        } else {
          ((float*)Cout)[row * NC + col] = v + bvals[n];
        }
      }
    }
  }
}

// ---------------- flash attention (LDS P round-trip) ----------------
__global__ __launch_bounds__(512) void attn(
    const f16* __restrict__ Qp, const f16* __restrict__ Kp,
    const f16* __restrict__ Vt, f16* __restrict__ O)
{
  const int LK = 72;
  const int LV = 136;
  const int LP = 136;
  __shared__ f16 Ks[128 * 72];
  __shared__ f16 Vs[64 * 136];
  __shared__ f16 Ps[8 * 16 * 136];
  const int tid = threadIdx.x;
  const int w = tid >> 6, lane = tid & 63;
  const int g = lane >> 4, q = lane & 15;
  const int qt = blockIdx.x, h = blockIdx.y, b = blockIdx.z;
  const float sc = 0.051031036307982884f * 1.4426950408889634f;
  const size_t qrow0 = (size_t)b * 4096 + qt * 128 + w * 16;
  f16x8 qf[2];
#pragma unroll
  for (int ks = 0; ks < 2; ++ks)
    qf[ks] = *(const f16x8*)(Qp + (qrow0 + q) * NC + h * 64 + ks * 32 + g * 8);
  f32x4 oa[4] = {};
  float m_run = -INFINITY, l_run = 0.f;
  for (int ch = 0; ch < 4; ++ch) {
    const size_t kb = (size_t)b * 512 + ch * 128;
    __syncthreads();
#pragma unroll
    for (int i = tid; i < 1024; i += 512) {
      const int j = i >> 3, blk = i & 7;
      *(f16x8*)&Ks[j * LK + blk * 8] = *(const f16x8*)&Kp[(kb + j) * NC + h * 64 + blk * 8];
    }
#pragma unroll
    for (int i = tid; i < 1024; i += 512) {
      const int dh = i >> 4, blk = i & 15;
      *(f16x8*)&Vs[dh * LV + blk * 8] =
          *(const f16x8*)&Vt[((size_t)b * NC + h * 64 + dh) * 512 + ch * 128 + blk * 8];
    }
    __syncthreads();
    f32x4 st[8] = {};
#pragma unroll
    for (int ks = 0; ks < 2; ++ks) {
#pragma unroll
      for (int m = 0; m < 8; ++m) {
        const f16x8 kf = *(const f16x8*)&Ks[(m * 16 + q) * LK + (4 * ks + g) * 8];
        st[m] = MFMA16(kf, qf[ks], st[m]);
      }
    }
    float tv[8][4];
    float cmax = -INFINITY;
#pragma unroll
    for (int m = 0; m < 8; ++m)
#pragma unroll
      for (int r = 0; r < 4; ++r) { tv[m][r] = st[m][r] * sc; cmax = fmaxf(cmax, tv[m][r]); }
    cmax = fmaxf(cmax, __shfl_xor(cmax, 16));
    cmax = fmaxf(cmax, __shfl_xor(cmax, 32));
    const float mnew = fmaxf(m_run, cmax);
    const float fac = exp2f(m_run - mnew);
    float psum = 0.f;
#pragma unroll
    for (int m = 0; m < 8; ++m) {
      const float p0 = exp2f(tv[m][0] - mnew), p1 = exp2f(tv[m][1] - mnew);
      const float p2 = exp2f(tv[m][2] - mnew), p3 = exp2f(tv[m][3] - mnew);
      psum += (p0 + p1) + (p2 + p3);
      f16* pr = &Ps[(w * 16 + q) * LP + m * 16 + 4 * g];
      pr[0] = (f16)p0; pr[1] = (f16)p1; pr[2] = (f16)p2; pr[3] = (f16)p3;
    }
    psum += __shfl_xor(psum, 16);
    psum += __shfl_xor(psum, 32);
    l_run = l_run * fac + psum;
    m_run = mnew;
#pragma unroll
    for (int r = 0; r < 4; ++r) {
      const float fr = __shfl(fac, g * 4 + r);
#pragma unroll
      for (int n = 0; n < 4; ++n) oa[n][r] *= fr;
    }
    __syncthreads();
#pragma unroll
    for (int ks = 0; ks < 4; ++ks) {
      const f16x8 pa = *(const f16x8*)&Ps[(w * 16 + q) * LP + ks * 32 + g * 8];
#pragma unroll
      for (int n = 0; n < 4; ++n) {
        const f16x8 vf = *(const f16x8*)&Vs[(n * 16 + q) * LV + ks * 32 + g * 8];
        oa[n] = MFMA16(pa, vf, oa[n]);
      }
    }
  }
  const float linv = 1.0f / l_run;
#pragma unroll
  for (int r = 0; r < 4; ++r) {
    const float lr = __shfl(linv, g * 4 + r);
    const size_t row = qrow0 + 4 * g + r;
#pragma unroll
    for (int n = 0; n < 4; ++n)
      O[row * NC + h * 64 + n * 16 + q] = (f16)(oa[n][r] * lr);
  }
}

// ---------------- launch ----------------
extern "C" void kernel_launch(void* const* d_in, const int* in_sizes, int n_in,
                              void* d_out, int out_size, void* d_ws, size_t ws_size,
                              hipStream_t stream) {
  const float* x   = (const float*)d_in[0];
  const float* cqw = (const float*)d_in[1];
  const float* ckw = (const float*)d_in[2];
  const float* cvw = (const float*)d_in[3];
  const float* bqg = (const float*)d_in[4],  *bqb = (const float*)d_in[5];
  const float* bqm = (const float*)d_in[6],  *bqv = (const float*)d_in[7];
  const float* bkg = (const float*)d_in[8],  *bkb = (const float*)d_in[9];
  const float* bkm = (const float*)d_in[10], *bkv = (const float*)d_in[11];
  const float* bvg = (const float*)d_in[12], *bvb = (const float*)d_in[13];
  const float* bvm = (const float*)d_in[14], *bvv = (const float*)d_in[15];
  const float* wq = (const float*)d_in[16];
  const float* wk = (const float*)d_in[17];
  const float* wv = (const float*)d_in[18];
  const float* pw = (const float*)d_in[19];
  const float* pb = (const float*)d_in[20];

  f16* q_tok = (f16*)d_out;                              // lo half (25 MB)
  f16* Qp    = (f16*)((char*)d_out + 25165824);          // hi half (25 MB)

  char* ws = (char*)d_ws;
  f16* wq_h  = (f16*)(ws + 0);
  f16* wk_h  = (f16*)(ws + 294912);
  f16* wv_h  = (f16*)(ws + 589824);
  f16* pw_h  = (f16*)(ws + 884736);
  f16* k_tok = (f16*)(ws + 1179648);
  f16* v_tok = (f16*)(ws + 4325376);
  f16* Kp    = (f16*)(ws + 7471104);
  f16* Vt    = (f16*)(ws + 10616832);
  f16* Oi    = (f16*)(ws + 13762560);
  float* wqT = (float*)(ws + 38928384);   // 41472 B each
  float* wkT = (float*)(ws + 38969856);
  float* wvT = (float*)(ws + 39011328);   // ws total 39,052,800 B

  cvt_w<<<dim3(576), dim3(256), 0, stream>>>(wq, wk, wv, pw, wq_h, wk_h, wv_h, pw_h, 147456);
  cvt_wt<<<dim3(27), dim3(384), 0, stream>>>(cqw, ckw, cvw, wqT, wkT, wvT);
  conv_fused<<<dim3(64, 8, 2), dim3(384), 0, stream>>>(
      x, wqT, wkT, wvT,
      bqg, bqb, bqm, bqv, bkg, bkb, bkm, bkv, bvg, bvb, bvm, bvv,
      q_tok, k_tok, v_tok);
  gemm_bt<0><<<dim3(3, 256), dim3(256), 0, stream>>>(q_tok, wq_h, Qp, nullptr);
  gemm_bt<0><<<dim3(3, 32),  dim3(256), 0, stream>>>(k_tok, wk_h, Kp, nullptr);
  gemm_bt<1><<<dim3(3, 32),  dim3(256), 0, stream>>>(v_tok, wv_h, Vt, nullptr);
  attn<<<dim3(32, 6, 8), dim3(512), 0, stream>>>(Qp, Kp, Vt, Oi);
  gemm_bt<2><<<dim3(3, 256), dim3(256), 0, stream>>>(Oi, pw_h, d_out, pb);
}

// Round 8
// 180.425 us; speedup vs baseline: 1.2829x; 1.1125x over previous
//
#include <hip/hip_runtime.h>
#include <hip/hip_bf16.h>
#include <stdint.h>

// Round 8: reinstate R1's validated fast machinery (bit-identical-to-R2 proof):
// gemm_bt: global_load_lds(16B) + XOR-swizzled LDS; attn: same staging +
// register P-repack (no Ps LDS, 32 KB LDS, 2 barriers/chunk).
// conv_fused kept from R7 (79 us) for clean attribution.

typedef _Float16 f16;
typedef _Float16 f16x8 __attribute__((ext_vector_type(8)));
typedef float f32x4 __attribute__((ext_vector_type(4)));
typedef uint32_t u32;
typedef uint32_t u32x4 __attribute__((ext_vector_type(4)));

#define NC 384
#define MFMA16(A_,B_,C_) __builtin_amdgcn_mfma_f32_16x16x32_f16((A_),(B_),(C_),0,0,0)

__device__ __forceinline__ void gll16(const void* g, void* l) {
  __builtin_amdgcn_global_load_lds(
      (__attribute__((address_space(1))) void*)g,
      (__attribute__((address_space(3))) void*)l, 16, 0, 0);
}

__device__ __forceinline__ u32 pkf16(float lo, float hi) {
  unsigned short a = __builtin_bit_cast(unsigned short, (f16)lo);
  unsigned short b = __builtin_bit_cast(unsigned short, (f16)hi);
  return (u32)a | ((u32)b << 16);
}

// ---------------- weight fp32 -> f16 convert ----------------
__global__ __launch_bounds__(256) void cvt_w(
    const float* __restrict__ s0, const float* __restrict__ s1,
    const float* __restrict__ s2, const float* __restrict__ s3,
    f16* __restrict__ d0, f16* __restrict__ d1,
    f16* __restrict__ d2, f16* __restrict__ d3, int n)
{
  int i = blockIdx.x * 256 + threadIdx.x;
  if (i < n) { d0[i] = (f16)s0[i]; d1[i] = (f16)s1[i]; d2[i] = (f16)s2[i]; d3[i] = (f16)s3[i]; }
}

// ---------------- conv-weight transpose [384][27] -> [27][384] ----------------
__global__ __launch_bounds__(384) void cvt_wt(
    const float* __restrict__ wq, const float* __restrict__ wk, const float* __restrict__ wv,
    float* __restrict__ qT, float* __restrict__ kT, float* __restrict__ vT)
{
  const int c = threadIdx.x;
  const int t = blockIdx.x;   // 0..26
  qT[t * 384 + c] = wq[c * 27 + t];
  kT[t * 384 + c] = wk[c * 27 + t];
  vT[t * 384 + c] = wv[c * 27 + t];
}

// ---------------- fused depthwise conv3d + BN (R7 version) ----------------
__global__ __launch_bounds__(384, 2) void conv_fused(
    const float* __restrict__ x,
    const float* __restrict__ wqT, const float* __restrict__ wkT, const float* __restrict__ wvT,
    const float* __restrict__ bqg, const float* __restrict__ bqb,
    const float* __restrict__ bqm, const float* __restrict__ bqv,
    const float* __restrict__ bkg, const float* __restrict__ bkb,
    const float* __restrict__ bkm, const float* __restrict__ bkv,
    const float* __restrict__ bvg, const float* __restrict__ bvb,
    const float* __restrict__ bvm, const float* __restrict__ bvv,
    f16* __restrict__ qout, f16* __restrict__ kout, f16* __restrict__ vout)
{
  const int c = threadIdx.x;
  const int th = blockIdx.x >> 3, tw = blockIdx.x & 7;
  const int b = blockIdx.y;
  const int z0 = blockIdx.z * 8;
  const int h0 = th * 2, w0 = tw * 2;

  float wqr[27], wkr[27], wvr[27];
#pragma unroll
  for (int t = 0; t < 27; ++t) {
    wqr[t] = wqT[t * 384 + c];
    wkr[t] = wkT[t * 384 + c];
    wvr[t] = wvT[t * 384 + c];
  }
  const float invq = bqg[c] * rsqrtf(bqv[c] + 1e-5f), betq = bqb[c] - bqm[c] * invq;
  const float invk = bkg[c] * rsqrtf(bkv[c] + 1e-5f), betk = bkb[c] - bkm[c] * invk;
  const float invv = bvg[c] * rsqrtf(bvv[c] + 1e-5f), betv = bvb[c] - bvm[c] * invv;

  bool hok[4], wok[4];
#pragma unroll
  for (int a = 0; a < 4; ++a) {
    hok[a] = (unsigned)(h0 - 1 + a) < 16u;
    wok[a] = (unsigned)(w0 - 1 + a) < 16u;
  }
  const float* xb = x + (size_t)b * 4096 * NC + c;

  float win[3][4][4];
  auto ldplane = [&](int s, int iz) {
    const bool zok = (unsigned)iz < 16u;
#pragma unroll
    for (int a = 0; a < 4; ++a)
#pragma unroll
      for (int e = 0; e < 4; ++e) {
        float v = 0.f;
        if (zok && hok[a] && wok[e])
          v = xb[(size_t)((h0 - 1 + a) * 256 + (w0 - 1 + e) * 16 + iz) * NC];
        win[s][a][e] = v;
      }
  };
  ldplane(2, z0 - 1);
  ldplane(0, z0);

#pragma unroll
  for (int zr = 0; zr < 8; ++zr) {
    const int z = z0 + zr;
    const int snew = (zr + 1) % 3;
    ldplane(snew, z + 1);
    float aq00 = 0.f, aq01 = 0.f, aq10 = 0.f, aq11 = 0.f;
    float ak = 0.f, av = 0.f;
#pragma unroll
    for (int p = 0; p < 3; ++p) {
      const int s = (zr - 1 + p + 3) % 3;
#pragma unroll
      for (int a = 0; a < 3; ++a)
#pragma unroll
        for (int e = 0; e < 3; ++e) {
          const float w00 = win[s][a][e],     w01 = win[s][a][e + 1];
          const float w10 = win[s][a + 1][e], w11 = win[s][a + 1][e + 1];
          const float cq = wqr[a * 9 + e * 3 + p];
          aq00 += w00 * cq; aq01 += w01 * cq;
          aq10 += w10 * cq; aq11 += w11 * cq;
          if ((zr & 1) == 0) {
            ak += w00 * wkr[a * 9 + e * 3 + p];
            av += w00 * wvr[a * 9 + e * 3 + p];
          }
        }
    }
    const size_t qb = (size_t)b * 4096;
    qout[(qb + (h0 + 0) * 256 + (w0 + 0) * 16 + z) * NC + c] = (f16)(aq00 * invq + betq);
    qout[(qb + (h0 + 0) * 256 + (w0 + 1) * 16 + z) * NC + c] = (f16)(aq01 * invq + betq);
    qout[(qb + (h0 + 1) * 256 + (w0 + 0) * 16 + z) * NC + c] = (f16)(aq10 * invq + betq);
    qout[(qb + (h0 + 1) * 256 + (w0 + 1) * 16 + z) * NC + c] = (f16)(aq11 * invq + betq);
    if ((zr & 1) == 0) {
      const size_t t = (size_t)b * 512 + (th * 8 + tw) * 8 + (z >> 1);
      kout[t * NC + c] = (f16)(ak * invk + betk);
      vout[t * NC + c] = (f16)(av * invv + betv);
    }
  }
}

// ---------------- GEMM (R1 version): gll16 staging + XOR-swizzled LDS ----------------
// MODE 0: f16 out; MODE 1: f16 transposed out C[b][col][t]; MODE 2: fp32 out + bias.
template<int MODE>
__global__ __launch_bounds__(256) void gemm_bt(
    const f16* __restrict__ A, const f16* __restrict__ Bw,
    void* __restrict__ Cout, const float* __restrict__ bias)
{
  __shared__ f16 As[128 * 64];
  __shared__ f16 Bs[128 * 64];
  const int tid = threadIdx.x;
  const int w = tid >> 6, lane = tid & 63;
  const int g = lane >> 4, q = lane & 15;
  const int wr = w >> 1, wc = w & 1;
  const size_t brow = (size_t)blockIdx.y * 128;
  const int bcol = blockIdx.x * 128;
  const int srow = lane >> 3;                 // row within 8-row stripe
  const int sbb  = (lane & 7) ^ (srow & 7);   // inverse-swizzled source block
  f32x4 acc[4][4] = {};
  for (int kt = 0; kt < 6; ++kt) {
    const int k0 = kt * 64;
#pragma unroll
    for (int j = 0; j < 4; ++j) {
      const int s = w * 4 + j;                // stripe 0..15 (8 rows each)
      gll16(A  + (brow + (size_t)(s * 8 + srow)) * NC + k0 + sbb * 8, (char*)As + s * 1024);
      gll16(Bw + (size_t)(bcol + s * 8 + srow) * NC + k0 + sbb * 8, (char*)Bs + s * 1024);
    }
    __syncthreads();
#pragma unroll
    for (int ks = 0; ks < 2; ++ks) {
      f16x8 af[4], bfr[4];
      const int bb = ((g + 4 * ks) ^ (q & 7)) * 16;
#pragma unroll
      for (int m = 0; m < 4; ++m) {
        af[m]  = *(const f16x8*)((const char*)As + (wr * 64 + m * 16 + q) * 128 + bb);
        bfr[m] = *(const f16x8*)((const char*)Bs + (wc * 64 + m * 16 + q) * 128 + bb);
      }
#pragma unroll
      for (int m = 0; m < 4; ++m)
#pragma unroll
        for (int n = 0; n < 4; ++n)
          acc[m][n] = MFMA16(af[m], bfr[n], acc[m][n]);
    }
    __syncthreads();
  }
  float bvals[4];
  if (MODE == 2) {
#pragma unroll
    for (int n = 0; n < 4; ++n) bvals[n] = bias[bcol + wc * 64 + n * 16 + q];
  }
#pragma unroll
  for (int m = 0; m < 4; ++m) {
#pragma unroll
    for (int n = 0; n < 4; ++n) {
#pragma unroll
      for (int r = 0; r < 4; ++r) {
        const size_t row = brow + wr * 64 + m * 16 + 4 * g + r;
        const int col = bcol + wc * 64 + n * 16 + q;
        const float v = acc[m][n][r];
        if (MODE == 0) {
          ((f16*)Cout)[row * NC + col] = (f16)v;
        } else if (MODE == 1) {
          const size_t bi = row >> 9, t = row & 511;
          ((f16*)Cout)[(bi * NC + col) * 512 + t] = (f16)v;
        } else {
          ((float*)Cout)[row * NC + col] = v + bvals[n];
        }
      }
    }
  }
}

// ---------------- flash attention (R1 version): gll16 + register P-repack ----------------
__global__ __launch_bounds__(512) void attn(
    const f16* __restrict__ Qp, const f16* __restrict__ Kp,
    const f16* __restrict__ Vt, f16* __restrict__ O)
{
  __shared__ f16 Ks[128 * 64];   // [j][d], 8 16B-blocks/row, blk ^= (j&7)
  __shared__ f16 Vs[64 * 128];   // [dh][j], 16 blocks/row, blk low3 ^= (dh&7)
  const int tid = threadIdx.x;
  const int w = tid >> 6, lane = tid & 63;
  const int g = lane >> 4, q = lane & 15;
  const int qt = blockIdx.x, h = blockIdx.y, b = blockIdx.z;
  const float sc = 0.051031036307982884f * 1.4426950408889634f; // 384^-0.5 * log2(e)
  const size_t qrow0 = (size_t)b * 4096 + qt * 128 + w * 16;
  f16x8 qf[2];
#pragma unroll
  for (int ks = 0; ks < 2; ++ks)
    qf[ks] = *(const f16x8*)(Qp + (qrow0 + q) * NC + h * 64 + ks * 32 + g * 8);
  f32x4 oa[4] = {};
  float m_run = -INFINITY, l_run = 0.f;
  const int srowK = lane >> 3;
  const int sbbK = (lane & 7) ^ (srowK & 7);
  for (int ch = 0; ch < 4; ++ch) {
    const size_t kb = (size_t)b * 512 + ch * 128;
#pragma unroll
    for (int j2 = 0; j2 < 2; ++j2) {
      const int s = w * 2 + j2;  // stripes 0..15
      gll16(Kp + (kb + (size_t)(s * 8 + srowK)) * NC + h * 64 + sbbK * 8, (char*)Ks + s * 1024);
      const int dh = s * 4 + (lane >> 4);
      const int sbbV = (lane & 15) ^ (dh & 7);
      gll16(Vt + ((size_t)b * NC + h * 64 + dh) * 512 + ch * 128 + sbbV * 8, (char*)Vs + s * 1024);
    }
    __syncthreads();
    // S^T: 8 j-tiles x 16 q-rows
    f32x4 st[8];
    const f32x4 zero = {0.f, 0.f, 0.f, 0.f};
#pragma unroll
    for (int m = 0; m < 8; ++m) st[m] = zero;
#pragma unroll
    for (int ks = 0; ks < 2; ++ks) {
      const int bb = ((g + 4 * ks) ^ (q & 7)) * 16;
#pragma unroll
      for (int m = 0; m < 8; ++m) {
        const f16x8 kf = *(const f16x8*)((const char*)Ks + (m * 16 + q) * 128 + bb);
        st[m] = MFMA16(kf, qf[ks], st[m]);
      }
    }
    // online softmax (lane owns q-row i=q; j = 16m + 4g + r)
    float tv[8][4];
    float cmax = -INFINITY;
#pragma unroll
    for (int m = 0; m < 8; ++m)
#pragma unroll
      for (int r = 0; r < 4; ++r) { tv[m][r] = st[m][r] * sc; cmax = fmaxf(cmax, tv[m][r]); }
    cmax = fmaxf(cmax, __shfl_xor(cmax, 16));
    cmax = fmaxf(cmax, __shfl_xor(cmax, 32));
    const float mnew = fmaxf(m_run, cmax);
    const float fac = exp2f(m_run - mnew);
    float psum = 0.f;
    u32 pw[8][2];
#pragma unroll
    for (int m = 0; m < 8; ++m) {
      const float p0 = exp2f(tv[m][0] - mnew), p1 = exp2f(tv[m][1] - mnew);
      const float p2 = exp2f(tv[m][2] - mnew), p3 = exp2f(tv[m][3] - mnew);
      psum += (p0 + p1) + (p2 + p3);
      pw[m][0] = pkf16(p0, p1);
      pw[m][1] = pkf16(p2, p3);
    }
    psum += __shfl_xor(psum, 16);
    psum += __shfl_xor(psum, 32);
    l_run = l_run * fac + psum;
    m_run = mnew;
    // rescale O (O-tile row = 4g+r -> factor lives at lane 4g+r)
#pragma unroll
    for (int r = 0; r < 4; ++r) {
      const float fr = __shfl(fac, g * 4 + r);
#pragma unroll
      for (int n = 0; n < 4; ++n) oa[n][r] *= fr;
    }
    // repack P (S^T C-layout) into PV A-frags via cross-g shuffles
    const int srcA = (2 * (g & 1)) * 16 + q;
    const int srcB = srcA + 16;
#pragma unroll
    for (int ks = 0; ks < 4; ++ks) {
      const int tA = 2 * ks, tB = 2 * ks + 1;
      const u32 a0 = __shfl(pw[tA][0], srcA), a1 = __shfl(pw[tA][1], srcA);
      const u32 b0 = __shfl(pw[tB][0], srcA), b1 = __shfl(pw[tB][1], srcA);
      const u32 c0 = __shfl(pw[tA][0], srcB), c1 = __shfl(pw[tA][1], srcB);
      const u32 d0 = __shfl(pw[tB][0], srcB), d1 = __shfl(pw[tB][1], srcB);
      const bool hi = (g >> 1);
      const u32x4 pi = { hi ? b0 : a0, hi ? b1 : a1, hi ? d0 : c0, hi ? d1 : c1 };
      const f16x8 pa = __builtin_bit_cast(f16x8, pi);
#pragma unroll
      for (int n = 0; n < 4; ++n) {
        const int bbv = ((4 * ks + g) ^ (q & 7)) * 16;
        const f16x8 vf = *(const f16x8*)((const char*)Vs + (n * 16 + q) * 256 + bbv);
        oa[n] = MFMA16(pa, vf, oa[n]);
      }
    }
    __syncthreads();
  }
  const float linv = 1.0f / l_run;
#pragma unroll
  for (int r = 0; r < 4; ++r) {
    const float lr = __shfl(linv, g * 4 + r);
    const size_t row = qrow0 + 4 * g + r;
#pragma unroll
    for (int n = 0; n < 4; ++n)
      O[row * NC + h * 64 + n * 16 + q] = (f16)(oa[n][r] * lr);
  }
}

// ---------------- launch ----------------
extern "C" void kernel_launch(void* const* d_in, const int* in_sizes, int n_in,
                              void* d_out, int out_size, void* d_ws, size_t ws_size,
                              hipStream_t stream) {
  const float* x   = (const float*)d_in[0];
  const float* cqw = (const float*)d_in[1];
  const float* ckw = (const float*)d_in[2];
  const float* cvw = (const float*)d_in[3];
  const float* bqg = (const float*)d_in[4],  *bqb = (const float*)d_in[5];
  const float* bqm = (const float*)d_in[6],  *bqv = (const float*)d_in[7];
  const float* bkg = (const float*)d_in[8],  *bkb = (const float*)d_in[9];
  const float* bkm = (const float*)d_in[10], *bkv = (const float*)d_in[11];
  const float* bvg = (const float*)d_in[12], *bvb = (const float*)d_in[13];
  const float* bvm = (const float*)d_in[14], *bvv = (const float*)d_in[15];
  const float* wq = (const float*)d_in[16];
  const float* wk = (const float*)d_in[17];
  const float* wv = (const float*)d_in[18];
  const float* pw = (const float*)d_in[19];
  const float* pb = (const float*)d_in[20];

  f16* q_tok = (f16*)d_out;                              // lo half (25 MB)
  f16* Qp    = (f16*)((char*)d_out + 25165824);          // hi half (25 MB)

  char* ws = (char*)d_ws;
  f16* wq_h  = (f16*)(ws + 0);
  f16* wk_h  = (f16*)(ws + 294912);
  f16* wv_h  = (f16*)(ws + 589824);
  f16* pw_h  = (f16*)(ws + 884736);
  f16* k_tok = (f16*)(ws + 1179648);
  f16* v_tok = (f16*)(ws + 4325376);
  f16* Kp    = (f16*)(ws + 7471104);
  f16* Vt    = (f16*)(ws + 10616832);
  f16* Oi    = (f16*)(ws + 13762560);
  float* wqT = (float*)(ws + 38928384);
  float* wkT = (float*)(ws + 38969856);
  float* wvT = (float*)(ws + 39011328);   // ws total 39,052,800 B

  cvt_w<<<dim3(576), dim3(256), 0, stream>>>(wq, wk, wv, pw, wq_h, wk_h, wv_h, pw_h, 147456);
  cvt_wt<<<dim3(27), dim3(384), 0, stream>>>(cqw, ckw, cvw, wqT, wkT, wvT);
  conv_fused<<<dim3(64, 8, 2), dim3(384), 0, stream>>>(
      x, wqT, wkT, wvT,
      bqg, bqb, bqm, bqv, bkg, bkb, bkm, bkv, bvg, bvb, bvm, bvv,
      q_tok, k_tok, v_tok);
  gemm_bt<0><<<dim3(3, 256), dim3(256), 0, stream>>>(q_tok, wq_h, Qp, nullptr);
  gemm_bt<0><<<dim3(3, 32),  dim3(256), 0, stream>>>(k_tok, wk_h, Kp, nullptr);
  gemm_bt<1><<<dim3(3, 32),  dim3(256), 0, stream>>>(v_tok, wv_h, Vt, nullptr);
  attn<<<dim3(32, 6, 8), dim3(512), 0, stream>>>(Qp, Kp, Vt, Oi);
  gemm_bt<2><<<dim3(3, 256), dim3(256), 0, stream>>>(Oi, pw_h, d_out, pb);
}